// Round 1
// baseline (632.321 us; speedup 1.0000x reference)
//
#include <hip/hip_runtime.h>

// ---------------------------------------------------------------------------
// LSTM cell: gates = [x|h] @ [Wx|Wh]^T + (bx+bh); i,f,o,c_ -> h_new, c_new
// Strategy: cast everything to bf16, one big MFMA GEMM (M=4096, N=8192,
// K=4096), fp32 gates in ws, then elementwise LSTM epilogue kernel.
// ---------------------------------------------------------------------------

typedef __bf16 bf16;
typedef __attribute__((ext_vector_type(8))) __bf16 bf16x8;
typedef __attribute__((ext_vector_type(4))) float f32x4;

#define BATCH 4096
#define SIZE  2048
#define KCAT  4096          // concatenated K (x | h)
#define NTOT  8192          // 4 gates * SIZE output columns
#define BM 128
#define BN 128
#define BK 32

__device__ __forceinline__ bf16 f2bf(float f) {
    unsigned u = __builtin_bit_cast(unsigned, f);
    u += 0x7fffu + ((u >> 16) & 1u);          // round-to-nearest-even
    unsigned short h = (unsigned short)(u >> 16);
    return __builtin_bit_cast(bf16, h);
}

__device__ __forceinline__ void gld_lds16(const bf16* g, bf16* l) {
    __builtin_amdgcn_global_load_lds(
        (__attribute__((address_space(1))) void*)(const_cast<bf16*>(g)),
        (__attribute__((address_space(3))) void*)l,
        16, 0, 0);
}

// ---------------------------------------------------------------------------
// Cast fp32 -> bf16 with K-concatenation: dst[row][0:khalf]=srcA[row],
// dst[row][khalf:2*khalf]=srcB[row]. Each thread converts 8 elements.
// ---------------------------------------------------------------------------
__global__ __launch_bounds__(256) void cast_concat(
    const float* __restrict__ srcA, const float* __restrict__ srcB,
    bf16* __restrict__ dst, int khalf)
{
    long t = (long)blockIdx.x * 256 + threadIdx.x;   // one per 8 elements
    long e = t * 8;
    int k2 = 2 * khalf;
    long row = e / k2;
    int col = (int)(e - row * k2);
    const float* src = (col < khalf) ? (srcA + row * khalf + col)
                                     : (srcB + row * khalf + (col - khalf));
    f32x4 v0 = *(const f32x4*)src;
    f32x4 v1 = *(const f32x4*)(src + 4);
    bf16x8 o;
    o[0] = f2bf(v0[0]); o[1] = f2bf(v0[1]); o[2] = f2bf(v0[2]); o[3] = f2bf(v0[3]);
    o[4] = f2bf(v1[0]); o[5] = f2bf(v1[1]); o[6] = f2bf(v1[2]); o[7] = f2bf(v1[3]);
    *(bf16x8*)(dst + e) = o;
}

// ---------------------------------------------------------------------------
// GEMM: gates[b][n] = sum_k A[b][k] * W[n][k] + bx[n] + bh[n]
// A: [4096][4096] bf16 (row-major, K contiguous), W: [8192][4096] bf16.
// 128x128 tile, 4 waves (2x2), each wave 64x64 via 4x4 frags of 16x16x32.
// m97 structure: single LDS buffer, 2-barrier K-loop, global_load_lds w=16.
// ---------------------------------------------------------------------------
__global__ __launch_bounds__(256) void gemm_gates(
    const bf16* __restrict__ A, const bf16* __restrict__ W,
    const float* __restrict__ bx, const float* __restrict__ bh,
    float* __restrict__ gates)
{
    __shared__ __align__(16) bf16 sA[BM * BK];   // 8 KB
    __shared__ __align__(16) bf16 sB[BN * BK];   // 8 KB

    const int tid  = threadIdx.x;
    const int lane = tid & 63;
    const int wave = tid >> 6;
    const int wm   = wave >> 1;                  // 0..1
    const int wn   = wave & 1;                   // 0..1

    const int m0 = blockIdx.y * BM;
    const int n0 = blockIdx.x * BN;

    // staging: thread t writes 16B at LDS elem offset t*8 (+2048 for round 1)
    const int selem = tid * 8;
    const int srow  = tid >> 2;                  // selem / 32
    const int scol  = (tid & 3) * 8;             // selem % 32
    const bf16* gA0 = A + (size_t)(m0 + srow) * KCAT + scol;
    const bf16* gB0 = W + (size_t)(n0 + srow) * KCAT + scol;

    f32x4 acc[4][4];
#pragma unroll
    for (int i = 0; i < 4; i++)
#pragma unroll
        for (int j = 0; j < 4; j++)
            acc[i][j] = (f32x4){0.f, 0.f, 0.f, 0.f};

    // LDS fragment read addressing (A-operand layout: m=lane&15, k=quad*8+j)
    const int fra = wm * 64 + (lane & 15);       // + i*16 per frag row-block
    const int frb = wn * 64 + (lane & 15);       // + j*16 per frag col-block
    const int frk = (lane >> 4) * 8;

    // stage tile 0
    gld_lds16(gA0,             &sA[selem]);
    gld_lds16(gA0 + (size_t)64 * KCAT, &sA[selem + 2048]);
    gld_lds16(gB0,             &sB[selem]);
    gld_lds16(gB0 + (size_t)64 * KCAT, &sB[selem + 2048]);

    const int NK = KCAT / BK;                    // 128
    for (int kt = 0; kt < NK; ++kt) {
        __syncthreads();                         // staging of tile kt complete

        bf16x8 a[4], b[4];
#pragma unroll
        for (int i = 0; i < 4; i++)
            a[i] = *(const bf16x8*)&sA[(fra + i * 16) * BK + frk];
#pragma unroll
        for (int j = 0; j < 4; j++)
            b[j] = *(const bf16x8*)&sB[(frb + j * 16) * BK + frk];

        __syncthreads();                         // all LDS reads done

        if (kt + 1 < NK) {                       // restage while MFMAs run
            const bf16* ga = gA0 + (size_t)(kt + 1) * BK;
            const bf16* gb = gB0 + (size_t)(kt + 1) * BK;
            gld_lds16(ga,                       &sA[selem]);
            gld_lds16(ga + (size_t)64 * KCAT,   &sA[selem + 2048]);
            gld_lds16(gb,                       &sB[selem]);
            gld_lds16(gb + (size_t)64 * KCAT,   &sB[selem + 2048]);
        }

#pragma unroll
        for (int i = 0; i < 4; i++)
#pragma unroll
            for (int j = 0; j < 4; j++)
                acc[i][j] = __builtin_amdgcn_mfma_f32_16x16x32_bf16(
                    a[i], b[j], acc[i][j], 0, 0, 0);
    }

    // epilogue: C/D layout col=lane&15, row=(lane>>4)*4+reg
    const int col0 = n0 + wn * 64 + (lane & 15);
    const int row0 = m0 + wm * 64 + (lane >> 4) * 4;
    float bias[4];
#pragma unroll
    for (int j = 0; j < 4; j++) {
        int col = col0 + j * 16;
        bias[j] = bx[col] + bh[col];
    }
#pragma unroll
    for (int i = 0; i < 4; i++) {
#pragma unroll
        for (int r = 0; r < 4; r++) {
            int row = row0 + i * 16 + r;
            float* dst = gates + (size_t)row * NTOT;
#pragma unroll
            for (int j = 0; j < 4; j++)
                dst[col0 + j * 16] = acc[i][j][r] + bias[j];
        }
    }
}

// ---------------------------------------------------------------------------
// Elementwise LSTM: gates [4096][8192] (i,f,o,c_ blocks of 2048 cols each)
// out[0 : B*S)        = h_new
// out[B*S : 2*B*S)    = c_new
// ---------------------------------------------------------------------------
__device__ __forceinline__ float sigm(float x) {
    return 1.f / (1.f + __expf(-x));
}
__device__ __forceinline__ float tanh_fast(float x) {
    float e = __expf(2.f * x);                   // inf-safe: 1 - 2/(e+1)
    return 1.f - 2.f / (e + 1.f);
}

__global__ __launch_bounds__(256) void lstm_ew(
    const float* __restrict__ gates, const float* __restrict__ c,
    float* __restrict__ out)
{
    int v = blockIdx.x * 256 + threadIdx.x;      // one per 4 elements
    int b  = v >> 9;                             // / (2048/4)
    int o  = (v & 511) * 4;
    const float* g = gates + (size_t)b * NTOT + o;
    f32x4 gi = *(const f32x4*)(g);
    f32x4 gf = *(const f32x4*)(g + 2048);
    f32x4 gg = *(const f32x4*)(g + 4096);
    f32x4 gc = *(const f32x4*)(g + 6144);
    f32x4 cv = *(const f32x4*)(c + (size_t)b * SIZE + o);
    f32x4 hn, cn;
#pragma unroll
    for (int k = 0; k < 4; k++) {
        float i_ = sigm(gi[k]);
        float f_ = sigm(gf[k]);
        float og = sigm(gg[k]);
        float cc = tanh_fast(gc[k]);
        float cnew = f_ * cv[k] + i_ * cc;
        cn[k] = cnew;
        hn[k] = og * tanh_fast(cnew);
    }
    *(f32x4*)(out + (size_t)b * SIZE + o) = hn;
    *(f32x4*)(out + (size_t)BATCH * SIZE + (size_t)b * SIZE + o) = cn;
}

// ---------------------------------------------------------------------------
extern "C" void kernel_launch(void* const* d_in, const int* in_sizes, int n_in,
                              void* d_out, int out_size, void* d_ws, size_t ws_size,
                              hipStream_t stream) {
    const float* x  = (const float*)d_in[0];
    const float* h  = (const float*)d_in[1];
    const float* c  = (const float*)d_in[2];
    const float* Wx = (const float*)d_in[3];   // (4,2048,2048) == (8192,2048)
    const float* bx = (const float*)d_in[4];   // (4,2048) == (8192)
    const float* Wh = (const float*)d_in[5];
    const float* bh = (const float*)d_in[6];
    float* out = (float*)d_out;

    char* w = (char*)d_ws;
    bf16*  Acat  = (bf16*)w;                                   // 32 MiB
    bf16*  Wcat  = (bf16*)(w + (size_t)33554432);              // 64 MiB
    float* gates = (float*)(w + (size_t)33554432 + 67108864);  // 128 MiB

    // 1) casts: A_cat = [x|h] (4096x4096), W_cat = [Wx|Wh] (8192x4096)
    cast_concat<<<(BATCH * (size_t)KCAT / 8) / 256, 256, 0, stream>>>(
        x, h, Acat, SIZE);
    cast_concat<<<(NTOT * (size_t)KCAT / 8) / 256, 256, 0, stream>>>(
        Wx, Wh, Wcat, SIZE);

    // 2) gates GEMM (M=4096, N=8192, K=4096) + bias
    dim3 grid(NTOT / BN, BATCH / BM);
    gemm_gates<<<grid, 256, 0, stream>>>(Acat, Wcat, bx, bh, gates);

    // 3) elementwise LSTM
    lstm_ew<<<(BATCH * (size_t)SIZE / 4) / 256, 256, 0, stream>>>(gates, c, out);
}

// Round 2
// 578.851 us; speedup vs baseline: 1.0924x; 1.0924x over previous
//
#include <hip/hip_runtime.h>

// ---------------------------------------------------------------------------
// LSTM cell, fully fused: gates = [x|h] @ [Wx|Wh]^T + (bx+bh), nonlinearity
// in the GEMM epilogue. W is cast to bf16 with gate-interleaved rows
// (n' = (s>>4)*64 + g*16 + (s&15)) so each lane's 4 N-fragments are the 4
// gates of the SAME (batch,s) element -> no cross-lane, no gates buffer.
// ---------------------------------------------------------------------------

typedef __bf16 bf16;
typedef __attribute__((ext_vector_type(8))) __bf16 bf16x8;
typedef __attribute__((ext_vector_type(4))) float f32x4;

#define BATCH 4096
#define SIZE  2048
#define KCAT  4096          // concatenated K (x | h)
#define NTOT  8192          // 4 gates * SIZE output columns
#define BM 128
#define BN 128
#define BK 32

__device__ __forceinline__ bf16 f2bf(float f) {
    unsigned u = __builtin_bit_cast(unsigned, f);
    u += 0x7fffu + ((u >> 16) & 1u);          // round-to-nearest-even
    unsigned short h = (unsigned short)(u >> 16);
    return __builtin_bit_cast(bf16, h);
}

__device__ __forceinline__ void gld_lds16(const bf16* g, bf16* l) {
    __builtin_amdgcn_global_load_lds(
        (__attribute__((address_space(1))) void*)(const_cast<bf16*>(g)),
        (__attribute__((address_space(3))) void*)l,
        16, 0, 0);
}

// ---------------------------------------------------------------------------
// Cast fp32 -> bf16, K-concat [srcA|srcB], all addressing via shifts.
// MODE 0: dst row = src row (activations: x|h).
// MODE 1: dst row n' -> src row g*2048 + s with s=(n'>>6)*16+(n'&15),
//         g=(n'>>4)&3  (weights, gate-interleaved).
// Each thread converts 8 contiguous dst elements. K fixed at 4096 (2048|2048).
// ---------------------------------------------------------------------------
template <int MODE>
__global__ __launch_bounds__(256) void cast_concat(
    const float* __restrict__ srcA, const float* __restrict__ srcB,
    bf16* __restrict__ dst)
{
    long t = (long)blockIdx.x * 256 + threadIdx.x;   // one per 8 elements
    long e = t << 3;
    long nprime = e >> 12;                           // dst row (K=4096)
    int  col    = (int)(e & 4095);
    long srow;
    if (MODE == 0) {
        srow = nprime;
    } else {
        int t16 = (int)(nprime & 15);
        int g   = (int)((nprime >> 4) & 3);
        long s  = ((nprime >> 6) << 4) + t16;
        srow = (long)g * SIZE + s;
    }
    const float* src = (col < SIZE) ? (srcA + (srow << 11) + col)
                                    : (srcB + (srow << 11) + (col - SIZE));
    f32x4 v0 = *(const f32x4*)src;
    f32x4 v1 = *(const f32x4*)(src + 4);
    bf16x8 o;
    o[0] = f2bf(v0[0]); o[1] = f2bf(v0[1]); o[2] = f2bf(v0[2]); o[3] = f2bf(v0[3]);
    o[4] = f2bf(v1[0]); o[5] = f2bf(v1[1]); o[6] = f2bf(v1[2]); o[7] = f2bf(v1[3]);
    *(bf16x8*)(dst + e) = o;
}

// ---------------------------------------------------------------------------
__device__ __forceinline__ float sigm(float x) {
    return 1.f / (1.f + __expf(-x));
}
__device__ __forceinline__ float tanh_fast(float x) {
    float e = __expf(2.f * x);                   // inf-safe: 1 - 2/(e+1)
    return 1.f - 2.f / (e + 1.f);
}

// ---------------------------------------------------------------------------
// Fused GEMM + LSTM: A [4096][4096] bf16, W4 [8192][4096] bf16 (gate-
// interleaved rows), c [4096][2048] f32. out = h_new (B*S) ++ c_new (B*S).
// 128x128 tile, 4 waves (2x2), 4x4 frags of 16x16x32 per wave.
// m97 structure: single LDS buffer, 2-barrier K-loop, global_load_lds w=16.
// ---------------------------------------------------------------------------
__global__ __launch_bounds__(256) void gemm_lstm(
    const bf16* __restrict__ A, const bf16* __restrict__ W,
    const float* __restrict__ bx, const float* __restrict__ bh,
    const float* __restrict__ c, float* __restrict__ out)
{
    __shared__ __align__(16) bf16 sA[BM * BK];   // 8 KB
    __shared__ __align__(16) bf16 sB[BN * BK];   // 8 KB

    const int tid  = threadIdx.x;
    const int lane = tid & 63;
    const int wave = tid >> 6;
    const int wm   = wave >> 1;                  // 0..1
    const int wn   = wave & 1;                   // 0..1

    const int m0 = blockIdx.y * BM;
    const int n0 = blockIdx.x * BN;

    // staging: thread t writes 16B at LDS elem offset t*8 (+2048 for round 1)
    const int selem = tid * 8;
    const int srow  = tid >> 2;                  // selem / 32
    const int scol  = (tid & 3) * 8;             // selem % 32
    const bf16* gA0 = A + (size_t)(m0 + srow) * KCAT + scol;
    const bf16* gB0 = W + (size_t)(n0 + srow) * KCAT + scol;

    f32x4 acc[4][4];
#pragma unroll
    for (int i = 0; i < 4; i++)
#pragma unroll
        for (int j = 0; j < 4; j++)
            acc[i][j] = (f32x4){0.f, 0.f, 0.f, 0.f};

    // LDS fragment read addressing (A-operand layout: m=lane&15, k=quad*8+j)
    const int fra = wm * 64 + (lane & 15);
    const int frb = wn * 64 + (lane & 15);
    const int frk = (lane >> 4) * 8;

    // stage tile 0
    gld_lds16(gA0,                     &sA[selem]);
    gld_lds16(gA0 + (size_t)64 * KCAT, &sA[selem + 2048]);
    gld_lds16(gB0,                     &sB[selem]);
    gld_lds16(gB0 + (size_t)64 * KCAT, &sB[selem + 2048]);

    const int NK = KCAT / BK;                    // 128
    for (int kt = 0; kt < NK; ++kt) {
        __syncthreads();                         // staging of tile kt complete

        bf16x8 a[4], b[4];
#pragma unroll
        for (int i = 0; i < 4; i++)
            a[i] = *(const bf16x8*)&sA[(fra + i * 16) * BK + frk];
#pragma unroll
        for (int j = 0; j < 4; j++)
            b[j] = *(const bf16x8*)&sB[(frb + j * 16) * BK + frk];

        __syncthreads();                         // all LDS reads done

        if (kt + 1 < NK) {                       // restage while MFMAs run
            const bf16* ga = gA0 + (size_t)(kt + 1) * BK;
            const bf16* gb = gB0 + (size_t)(kt + 1) * BK;
            gld_lds16(ga,                     &sA[selem]);
            gld_lds16(ga + (size_t)64 * KCAT, &sA[selem + 2048]);
            gld_lds16(gb,                     &sB[selem]);
            gld_lds16(gb + (size_t)64 * KCAT, &sB[selem + 2048]);
        }

#pragma unroll
        for (int i = 0; i < 4; i++)
#pragma unroll
            for (int j = 0; j < 4; j++)
                acc[i][j] = __builtin_amdgcn_mfma_f32_16x16x32_bf16(
                    a[i], b[j], acc[i][j], 0, 0, 0);
    }

    // ------------------------------------------------------------------
    // Epilogue. C/D layout: col=lane&15, row=(lane>>4)*4+reg.
    // This block's 128 cols of W4 cover s in [blockIdx.x*32, +32):
    //   wave chunk wn covers s = blockIdx.x*32 + wn*16 + (lane&15),
    //   and frag j IS gate j for that s.
    // ------------------------------------------------------------------
    const int s = blockIdx.x * 32 + wn * 16 + (lane & 15);
    const float b_i = bx[0 * SIZE + s] + bh[0 * SIZE + s];
    const float b_f = bx[1 * SIZE + s] + bh[1 * SIZE + s];
    const float b_o = bx[2 * SIZE + s] + bh[2 * SIZE + s];
    const float b_c = bx[3 * SIZE + s] + bh[3 * SIZE + s];

    const int row0 = m0 + wm * 64 + (lane >> 4) * 4;
    float* hout = out;
    float* cout = out + (size_t)BATCH * SIZE;

#pragma unroll
    for (int i = 0; i < 4; i++) {
#pragma unroll
        for (int r = 0; r < 4; r++) {
            const int row = row0 + i * 16 + r;
            const size_t idx = (size_t)row * SIZE + s;
            float i_ = sigm(acc[i][0][r] + b_i);
            float f_ = sigm(acc[i][1][r] + b_f);
            float o_ = sigm(acc[i][2][r] + b_o);
            float cc = tanh_fast(acc[i][3][r] + b_c);
            float cn = f_ * c[idx] + i_ * cc;
            hout[idx] = o_ * tanh_fast(cn);
            cout[idx] = cn;
        }
    }
}

// ---------------------------------------------------------------------------
extern "C" void kernel_launch(void* const* d_in, const int* in_sizes, int n_in,
                              void* d_out, int out_size, void* d_ws, size_t ws_size,
                              hipStream_t stream) {
    const float* x  = (const float*)d_in[0];
    const float* h  = (const float*)d_in[1];
    const float* c  = (const float*)d_in[2];
    const float* Wx = (const float*)d_in[3];   // (4,2048,2048)
    const float* bx = (const float*)d_in[4];   // (4,2048)
    const float* Wh = (const float*)d_in[5];
    const float* bh = (const float*)d_in[6];
    float* out = (float*)d_out;

    char* w = (char*)d_ws;
    bf16* Acat = (bf16*)w;                           // 32 MiB
    bf16* Wcat = (bf16*)(w + (size_t)33554432);      // 64 MiB

    // 1) casts: A_cat = [x|h] (4096x4096); W_cat gate-interleaved (8192x4096)
    cast_concat<0><<<(BATCH * (size_t)KCAT / 8) / 256, 256, 0, stream>>>(
        x, h, Acat);
    cast_concat<1><<<(NTOT * (size_t)KCAT / 8) / 256, 256, 0, stream>>>(
        Wx, Wh, Wcat);

    // 2) fused gates GEMM (M=4096, N=8192, K=4096) + bias + LSTM nonlinearity
    dim3 grid(NTOT / BN, BATCH / BM);
    gemm_lstm<<<grid, 256, 0, stream>>>(Acat, Wcat, bx, bh, c, out);
}